// Round 9
// baseline (124.792 us; speedup 1.0000x reference)
//
#include <hip/hip_runtime.h>
#include <cmath>

// Tiny transformer block, D=6, S=128, B=8192, fp32.
// R9 = R8's verified 16x16x16 MFMA flash core, made persistent:
//  - grid = B/4 blocks; each block loops over NB=4 batches. Next batch's x
//    is prefetched right after staging -> HBM latency overlaps flash+epilogue.
//  - Weight loads are loop-invariant -> hoisted to SGPRs once per block.
//  - Epilogue rows remapped to the wave that computed them (wave0: tiles
//    {0,3,4,7}; wave1: {1,2,5,6}) -> epilogue runs right after flash, no
//    third barrier. x crosses the remap via obuf cols 8..13 (staged pre-
//    barrier). Two barriers per iteration.

typedef float    v2f  __attribute__((ext_vector_type(2)));
typedef float    f4v  __attribute__((ext_vector_type(4)));
typedef short    s4v  __attribute__((ext_vector_type(4)));   // 4 bf16 = 2 VGPRs
typedef uint32_t u2   __attribute__((ext_vector_type(2)));

constexpr int D = 6;
constexpr int S = 128;
constexpr int NB = 4;               // batches per persistent block
#define EPS 1e-5f
#define RSQRT_D 0.4082482904638631f   // 1/sqrt(6)
#define LOG2E   1.4426950408889634f

#define EXP2F(x) __builtin_amdgcn_exp2f(x)
#define RCPF(x)  __builtin_amdgcn_rcpf(x)
#define PKFMA(a, b, c) __builtin_elementwise_fma((a), (b), (c))

union UA { uint32_t u[2]; u2 h; s4v v; };

__device__ __forceinline__ uint32_t pkbf(float hi, float lo) {
    return __builtin_amdgcn_perm(__builtin_bit_cast(uint32_t, hi),
                                 __builtin_bit_cast(uint32_t, lo),
                                 0x07060302u);
}
__device__ __forceinline__ uint16_t bf16t(float x) {
    return (uint16_t)(__builtin_bit_cast(uint32_t, x) >> 16);
}

__device__ __forceinline__ f4v mfma16(s4v a, s4v b, f4v c) {
#if __has_builtin(__builtin_amdgcn_mfma_f32_16x16x16bf16_1k)
    return __builtin_amdgcn_mfma_f32_16x16x16bf16_1k(a, b, c, 0, 0, 0);
#else
    f4v d;
    asm volatile("v_mfma_f32_16x16x16_bf16 %0, %1, %2, %3\n\t"
                 "s_nop 7\n\ts_nop 2"
                 : "=v"(d) : "v"(a), "v"(b), "v"(c));
    return d;
#endif
}

// Dual-stream pass over q-tiles QA < QB; fragments register-resident.
template<int QA, int QB>
__device__ __forceinline__ void attn_pair(
    const UA (&kf)[8], const UA (&vf)[8],
    UA qfA, UA qfB, float (*obuf)[14], int l15, int lq)
{
    const f4v z = {0.f, 0.f, 0.f, 0.f};
    f4v OA = z, OB = z;
    #pragma unroll
    for (int jt = 0; jt <= QB; ++jt) {
        f4v cB = mfma16(kf[jt].v, qfB.v, z);
        f4v cA;
        if (jt <= QA) cA = mfma16(kf[jt].v, qfA.v, z);
        float pB0 = EXP2F(cB[0]);
        float pB1 = EXP2F(cB[1]);
        float pB2 = EXP2F(cB[2]);
        float pB3 = EXP2F(cB[3]);
        if (jt == QB) {  // diagonal tile of B: causal mask
            pB0 = (lq * 4 + 0 > l15) ? 0.f : pB0;
            pB1 = (lq * 4 + 1 > l15) ? 0.f : pB1;
            pB2 = (lq * 4 + 2 > l15) ? 0.f : pB2;
            pB3 = (lq * 4 + 3 > l15) ? 0.f : pB3;
        }
        UA paB;
        paB.u[0] = pkbf(pB1, pB0);
        paB.u[1] = pkbf(pB3, pB2);
        OB = mfma16(paB.v, vf[jt].v, OB);
        if (jt <= QA) {
            float pA0 = EXP2F(cA[0]);
            float pA1 = EXP2F(cA[1]);
            float pA2 = EXP2F(cA[2]);
            float pA3 = EXP2F(cA[3]);
            if (jt == QA) {  // diagonal tile of A
                pA0 = (lq * 4 + 0 > l15) ? 0.f : pA0;
                pA1 = (lq * 4 + 1 > l15) ? 0.f : pA1;
                pA2 = (lq * 4 + 2 > l15) ? 0.f : pA2;
                pA3 = (lq * 4 + 3 > l15) ? 0.f : pA3;
            }
            UA paA;
            paA.u[0] = pkbf(pA1, pA0);
            paA.u[1] = pkbf(pA3, pA2);
            OA = mfma16(paA.v, vf[jt].v, OA);
        }
    }
    // O: lane col=d=l15 (col 6 holds the denominator), rows q=lq*4+r
    if (l15 < 7) {
        #pragma unroll
        for (int r = 0; r < 4; ++r) {
            obuf[QA * 16 + lq * 4 + r][l15] = OA[r];
            obuf[QB * 16 + lq * 4 + r][l15] = OB[r];
        }
    }
}

__global__ __launch_bounds__(S, 4) void txblock_kernel(
    const float* __restrict__ x,
    const float* __restrict__ ln1_w, const float* __restrict__ ln1_b,
    const float* __restrict__ wqkv,  const float* __restrict__ bqkv,
    const float* __restrict__ wo,    const float* __restrict__ bo,
    const float* __restrict__ ln2_w, const float* __restrict__ ln2_b,
    const float* __restrict__ w1,    const float* __restrict__ b1,
    const float* __restrict__ w2,    const float* __restrict__ b2,
    float* __restrict__ out)
{
    __shared__ uint32_t qlds[S][6];   // bf16 pairs + in-row zero pad
    __shared__ uint32_t klds[S][6];
    __shared__ uint16_t vt[8][S + 8]; // V^T d=0..5; row6=1.0; row7=0
    __shared__ float    obuf[S][14];  // cols 0..6: O+l; cols 8..13: staged x

    const int s = threadIdx.x;
    const int t  = s & 63;
    const int wv = s >> 6;
    // epilogue row owned by this thread (rows of this wave's q-tiles)
    const int rrow = wv ? (t + 16 + ((t >= 32) ? 32 : 0))
                        : (t + ((t >= 16) ? 32 : 0) + ((t >= 48) ? 32 : 0));

    const int l15 = s & 15;
    const int lq  = (s >> 4) & 3;
    const int aoff = (lq < 2) ? lq * 8 : 16;   // quads 2/3 -> zero pad
    const int vne  = (l15 < 7) ? l15 : 7;      // 0..5=V rows, 6=ones, 7=zeros

    size_t base = ((size_t)blockIdx.x * NB * S + s) * D;
    const float* xrow = x + base;

    // prefetch x for iteration 0
    v2f px01 = ((const v2f*)xrow)[0];
    v2f px23 = ((const v2f*)xrow)[1];
    v2f px45 = ((const v2f*)xrow)[2];

    for (int it = 0; it < NB; ++it) {
        const size_t bb = (size_t)blockIdx.x * NB + it;
        float xv[D] = {px01[0], px01[1], px23[0], px23[1], px45[0], px45[1]};

        // ---- ln1 ----
        float m = 0.f;
        #pragma unroll
        for (int d = 0; d < D; ++d) m += xv[d];
        m *= (1.0f / D);
        float var = 0.f;
        #pragma unroll
        for (int d = 0; d < D; ++d) { float tt = xv[d] - m; var += tt * tt; }
        var *= (1.0f / D);
        float rstd = rsqrtf(var + EPS);
        float h1[D];
        #pragma unroll
        for (int d = 0; d < D; ++d)
            h1[d] = (xv[d] - m) * rstd * ln1_w[d] + ln1_b[d];

        // ---- qkv projection (packed; weights hoisted to SGPRs by compiler) ----
        v2f aq[3], ak[3], av[3];
        #pragma unroll
        for (int jp = 0; jp < 3; ++jp) {
            aq[jp] = ((const v2f*)bqkv)[jp];
            ak[jp] = ((const v2f*)(bqkv + D))[jp];
            av[jp] = ((const v2f*)(bqkv + 2 * D))[jp];
        }
        #pragma unroll
        for (int d = 0; d < D; ++d) {
            const float* wrow = wqkv + d * 3 * D;
            v2f hd = {h1[d], h1[d]};
            #pragma unroll
            for (int jp = 0; jp < 3; ++jp) {
                aq[jp] = PKFMA(hd, ((const v2f*)wrow)[jp], aq[jp]);
                ak[jp] = PKFMA(hd, ((const v2f*)(wrow + D))[jp], ak[jp]);
                av[jp] = PKFMA(hd, ((const v2f*)(wrow + 2 * D))[jp], av[jp]);
            }
        }
        const v2f qscale = {RSQRT_D * LOG2E, RSQRT_D * LOG2E};

        // ---- stage Q, K, V^T, and x (for the remapped epilogue) ----
        #pragma unroll
        for (int jp = 0; jp < 3; ++jp) {
            v2f qs = aq[jp] * qscale;
            qlds[s][jp] = pkbf(qs[1], qs[0]);
            klds[s][jp] = pkbf(ak[jp][1], ak[jp][0]);
        }
        qlds[s][3] = 0; qlds[s][4] = 0; qlds[s][5] = 0;
        klds[s][3] = 0; klds[s][4] = 0; klds[s][5] = 0;
        vt[0][s] = bf16t(av[0][0]);
        vt[1][s] = bf16t(av[0][1]);
        vt[2][s] = bf16t(av[1][0]);
        vt[3][s] = bf16t(av[1][1]);
        vt[4][s] = bf16t(av[2][0]);
        vt[5][s] = bf16t(av[2][1]);
        vt[6][s] = 0x3F80;  // bf16 1.0 -> denominator column
        vt[7][s] = 0;
        *(v2f*)&obuf[s][8]  = px01;
        *(v2f*)&obuf[s][10] = px23;
        *(v2f*)&obuf[s][12] = px45;

        // ---- prefetch next batch's x (overlaps flash + epilogue) ----
        if (it + 1 < NB) {
            const float* xn = xrow + (size_t)(it + 1) * S * D;
            px01 = ((const v2f*)xn)[0];
            px23 = ((const v2f*)xn)[1];
            px45 = ((const v2f*)xn)[2];
        }
        __syncthreads();   // barrier 1: staging visible to both waves

        // ---- flash attention, fragments register-resident (R8 core) ----
        UA kf[8], vf[8];
        #pragma unroll
        for (int jt = 0; jt < 8; ++jt) {
            kf[jt].h = *(const u2*)((const char*)&klds[jt * 16 + l15][0] + aoff);
            vf[jt].h = *(const u2*)&vt[vne][jt * 16 + lq * 4];
        }
        if (wv == 0) {
            UA qA1, qB1, qA2, qB2;
            qA1.h = *(const u2*)((const char*)&qlds[0 * 16 + l15][0] + aoff);
            qB1.h = *(const u2*)((const char*)&qlds[7 * 16 + l15][0] + aoff);
            qA2.h = *(const u2*)((const char*)&qlds[3 * 16 + l15][0] + aoff);
            qB2.h = *(const u2*)((const char*)&qlds[4 * 16 + l15][0] + aoff);
            attn_pair<0, 7>(kf, vf, qA1, qB1, obuf, l15, lq);
            attn_pair<3, 4>(kf, vf, qA2, qB2, obuf, l15, lq);
        } else {
            UA qA1, qB1, qA2, qB2;
            qA1.h = *(const u2*)((const char*)&qlds[1 * 16 + l15][0] + aoff);
            qB1.h = *(const u2*)((const char*)&qlds[6 * 16 + l15][0] + aoff);
            qA2.h = *(const u2*)((const char*)&qlds[2 * 16 + l15][0] + aoff);
            qB2.h = *(const u2*)((const char*)&qlds[5 * 16 + l15][0] + aoff);
            attn_pair<1, 6>(kf, vf, qA1, qB1, obuf, l15, lq);
            attn_pair<2, 5>(kf, vf, qA2, qB2, obuf, l15, lq);
        }

        // ---- epilogue for the remapped row (same wave wrote its obuf) ----
        v2f rx01 = *(const v2f*)&obuf[rrow][8];
        v2f rx23 = *(const v2f*)&obuf[rrow][10];
        v2f rx45 = *(const v2f*)&obuf[rrow][12];
        v2f o01 = *(const v2f*)&obuf[rrow][0];
        v2f o23 = *(const v2f*)&obuf[rrow][2];
        v2f o45 = *(const v2f*)&obuf[rrow][4];
        float invl = RCPF(obuf[rrow][6]);
        v2f il = {invl, invl};
        o01 *= il; o23 *= il; o45 *= il;
        float av6[D] = {o01[0], o01[1], o23[0], o23[1], o45[0], o45[1]};

        v2f xvp[3] = {rx01, rx23, rx45};
        v2f x2p[3];
        #pragma unroll
        for (int dp = 0; dp < 3; ++dp) {
            v2f o = ((const v2f*)bo)[dp];
            #pragma unroll
            for (int e = 0; e < D; ++e) {
                v2f we = ((const v2f*)(wo + e * D))[dp];
                v2f ae = {av6[e], av6[e]};
                o = PKFMA(ae, we, o);
            }
            x2p[dp] = o + xvp[dp];
        }
        float x2[D] = {x2p[0][0], x2p[0][1], x2p[1][0], x2p[1][1], x2p[2][0], x2p[2][1]};

        float m2 = 0.f;
        #pragma unroll
        for (int d = 0; d < D; ++d) m2 += x2[d];
        m2 *= (1.0f / D);
        float var2 = 0.f;
        #pragma unroll
        for (int d = 0; d < D; ++d) { float tt = x2[d] - m2; var2 += tt * tt; }
        var2 *= (1.0f / D);
        float rstd2 = rsqrtf(var2 + EPS);
        float h2[D];
        #pragma unroll
        for (int d = 0; d < D; ++d)
            h2[d] = (x2[d] - m2) * rstd2 * ln2_w[d] + ln2_b[d];

        v2f ap[3];
        #pragma unroll
        for (int jp = 0; jp < 3; ++jp) {
            v2f a = ((const v2f*)b1)[jp];
            #pragma unroll
            for (int d = 0; d < D; ++d) {
                v2f wd = ((const v2f*)(w1 + d * D))[jp];
                v2f hd = {h2[d], h2[d]};
                a = PKFMA(hd, wd, a);
            }
            ap[jp] = a;
        }
        float g[D];
        #pragma unroll
        for (int j = 0; j < D; ++j) {
            float a = ap[j >> 1][j & 1];
            float tt = a * a;
            float in = fmaf(0.044715f * tt, a, a);
            float e  = EXP2F(in * -2.3022229f);
            float r  = RCPF(1.0f + e);
            g[j] = a * r;
        }
        float* orow = out + (bb * S + rrow) * D;
        #pragma unroll
        for (int dp = 0; dp < 3; ++dp) {
            v2f a = ((const v2f*)b2)[dp];
            #pragma unroll
            for (int e = 0; e < D; ++e) {
                v2f we = ((const v2f*)(w2 + e * D))[dp];
                v2f ge = {g[e], g[e]};
                a = PKFMA(ge, we, a);
            }
            ((v2f*)orow)[dp] = x2p[dp] + a;
        }
        __syncthreads();   // barrier 2: protect staging for next iteration
    }
}

extern "C" void kernel_launch(void* const* d_in, const int* in_sizes, int n_in,
                              void* d_out, int out_size, void* d_ws, size_t ws_size,
                              hipStream_t stream) {
    const float* x     = (const float*)d_in[0];
    const float* ln1_w = (const float*)d_in[1];
    const float* ln1_b = (const float*)d_in[2];
    const float* wqkv  = (const float*)d_in[3];
    const float* bqkv  = (const float*)d_in[4];
    const float* wo    = (const float*)d_in[5];
    const float* bo    = (const float*)d_in[6];
    const float* ln2_w = (const float*)d_in[7];
    const float* ln2_b = (const float*)d_in[8];
    const float* w1    = (const float*)d_in[9];
    const float* b1    = (const float*)d_in[10];
    const float* w2    = (const float*)d_in[11];
    const float* b2    = (const float*)d_in[12];
    float* out = (float*)d_out;

    const int B = in_sizes[0] / (S * D);
    const int grid = B / NB;   // B=8192 -> 2048 persistent blocks
    txblock_kernel<<<grid, S, 0, stream>>>(x, ln1_w, ln1_b, wqkv, bqkv, wo, bo,
                                           ln2_w, ln2_b, w1, b1, w2, b2, out);
}

// Round 10
// 111.911 us; speedup vs baseline: 1.1151x; 1.1151x over previous
//
#include <hip/hip_runtime.h>
#include <cmath>

// Tiny transformer block, D=6, S=128, B=8192, fp32.
// R10 = R6's verified flash core, restructured for the 64-VGPR occupancy
// cliff (occupancy steps at vgpr={64,128,256} -> 8/4/2 waves/SIMD):
//  - __launch_bounds__(128, 8): cap VGPRs at 64 -> 8 waves/SIMD (2x R6).
//  - obuf aliased onto qlds+klds (dead after fragment hoist): LDS 13.3->8.3KB
//    so LDS doesn't cap the doubled residency. Extra barrier after hoist.
//  - Live-state diet: all 4 qf + 8 kf hoisted (qlds/klds die early), vf read
//    per tile-step, x re-read in the epilogue, single O per stream.
//  - Math byte-identical to the verified core -> absmax must be 0.03125.

typedef float    v2f  __attribute__((ext_vector_type(2)));
typedef float    f4v  __attribute__((ext_vector_type(4)));
typedef short    s4v  __attribute__((ext_vector_type(4)));   // 4 bf16 = 2 VGPRs
typedef uint32_t u2   __attribute__((ext_vector_type(2)));

constexpr int D = 6;
constexpr int S = 128;
#define EPS 1e-5f
#define RSQRT_D 0.4082482904638631f   // 1/sqrt(6)
#define LOG2E   1.4426950408889634f

#define EXP2F(x) __builtin_amdgcn_exp2f(x)
#define RCPF(x)  __builtin_amdgcn_rcpf(x)
#define PKFMA(a, b, c) __builtin_elementwise_fma((a), (b), (c))

union UA { uint32_t u[2]; u2 h; s4v v; };

__device__ __forceinline__ uint32_t pkbf(float hi, float lo) {
    return __builtin_amdgcn_perm(__builtin_bit_cast(uint32_t, hi),
                                 __builtin_bit_cast(uint32_t, lo),
                                 0x07060302u);
}
__device__ __forceinline__ uint16_t bf16t(float x) {
    return (uint16_t)(__builtin_bit_cast(uint32_t, x) >> 16);
}

__device__ __forceinline__ f4v mfma16(s4v a, s4v b, f4v c) {
#if __has_builtin(__builtin_amdgcn_mfma_f32_16x16x16bf16_1k)
    return __builtin_amdgcn_mfma_f32_16x16x16bf16_1k(a, b, c, 0, 0, 0);
#else
    f4v d;
    asm volatile("v_mfma_f32_16x16x16_bf16 %0, %1, %2, %3\n\t"
                 "s_nop 7\n\ts_nop 2"
                 : "=v"(d) : "v"(a), "v"(b), "v"(c));
    return d;
#endif
}

// Dual-stream pass over q-tiles QA < QB; kf register-resident, vf read
// per step (one b64 per jt, shared by both streams). Single O per stream.
template<int QA, int QB>
__device__ __forceinline__ void attn_pair(
    const UA (&kf)[8], const uint16_t (*vt)[S + 8], int vne,
    UA qfA, UA qfB, float (*obuf)[10], int l15, int lq)
{
    const f4v z = {0.f, 0.f, 0.f, 0.f};
    f4v OA = z, OB = z;
    #pragma unroll
    for (int jt = 0; jt <= QB; ++jt) {
        UA vf; vf.h = *(const u2*)&vt[vne][jt * 16 + lq * 4];
        f4v cB = mfma16(kf[jt].v, qfB.v, z);
        f4v cA;
        if (jt <= QA) cA = mfma16(kf[jt].v, qfA.v, z);
        float pB0 = EXP2F(cB[0]);
        float pB1 = EXP2F(cB[1]);
        float pB2 = EXP2F(cB[2]);
        float pB3 = EXP2F(cB[3]);
        if (jt == QB) {  // diagonal tile of B: causal mask
            pB0 = (lq * 4 + 0 > l15) ? 0.f : pB0;
            pB1 = (lq * 4 + 1 > l15) ? 0.f : pB1;
            pB2 = (lq * 4 + 2 > l15) ? 0.f : pB2;
            pB3 = (lq * 4 + 3 > l15) ? 0.f : pB3;
        }
        UA paB;
        paB.u[0] = pkbf(pB1, pB0);
        paB.u[1] = pkbf(pB3, pB2);
        OB = mfma16(paB.v, vf.v, OB);
        if (jt <= QA) {
            float pA0 = EXP2F(cA[0]);
            float pA1 = EXP2F(cA[1]);
            float pA2 = EXP2F(cA[2]);
            float pA3 = EXP2F(cA[3]);
            if (jt == QA) {  // diagonal tile of A
                pA0 = (lq * 4 + 0 > l15) ? 0.f : pA0;
                pA1 = (lq * 4 + 1 > l15) ? 0.f : pA1;
                pA2 = (lq * 4 + 2 > l15) ? 0.f : pA2;
                pA3 = (lq * 4 + 3 > l15) ? 0.f : pA3;
            }
            UA paA;
            paA.u[0] = pkbf(pA1, pA0);
            paA.u[1] = pkbf(pA3, pA2);
            OA = mfma16(paA.v, vf.v, OA);
        }
    }
    // O: lane col=d=l15 (col 6 holds the denominator), rows q=lq*4+r
    if (l15 < 7) {
        #pragma unroll
        for (int r = 0; r < 4; ++r) {
            obuf[QA * 16 + lq * 4 + r][l15] = OA[r];
            obuf[QB * 16 + lq * 4 + r][l15] = OB[r];
        }
    }
}

__global__ __launch_bounds__(S, 8) void txblock_kernel(
    const float* __restrict__ x,
    const float* __restrict__ ln1_w, const float* __restrict__ ln1_b,
    const float* __restrict__ wqkv,  const float* __restrict__ bqkv,
    const float* __restrict__ wo,    const float* __restrict__ bo,
    const float* __restrict__ ln2_w, const float* __restrict__ ln2_b,
    const float* __restrict__ w1,    const float* __restrict__ b1,
    const float* __restrict__ w2,    const float* __restrict__ b2,
    float* __restrict__ out)
{
    // qk[0]=Q rows, qk[1]=K rows: 6 dwords [f01,f23,f45,0,0,0]; quads 2/3
    // read the zero pad at dwords 4..5. 24B stride -> conflict-free.
    // obuf (S x 10 floats = 5.0KB) ALIASES qk (6.0KB): qk is dead after the
    // fragment hoist; a barrier separates hoist reads from obuf writes.
    __shared__ uint32_t qk[2][S][6];
    __shared__ uint16_t vt[8][S + 8]; // V^T d=0..5; row6=1.0; row7=0
    float (*obuf)[10] = reinterpret_cast<float(*)[10]>(&qk[0][0][0]);

    const int b = blockIdx.x;
    const int s = threadIdx.x;
    const float* xrow = x + ((size_t)b * S + s) * D;
    float*      orow = out + ((size_t)b * S + s) * D;

    // ---- load x row ----
    v2f xv01 = ((const v2f*)xrow)[0];
    v2f xv23 = ((const v2f*)xrow)[1];
    v2f xv45 = ((const v2f*)xrow)[2];
    float xv[D] = {xv01[0], xv01[1], xv23[0], xv23[1], xv45[0], xv45[1]};

    // ---- ln1 ----
    float m = 0.f;
    #pragma unroll
    for (int d = 0; d < D; ++d) m += xv[d];
    m *= (1.0f / D);
    float var = 0.f;
    #pragma unroll
    for (int d = 0; d < D; ++d) { float t = xv[d] - m; var += t * t; }
    var *= (1.0f / D);
    float rstd = rsqrtf(var + EPS);
    float h1[D];
    #pragma unroll
    for (int d = 0; d < D; ++d)
        h1[d] = (xv[d] - m) * rstd * ln1_w[d] + ln1_b[d];

    // ---- qkv projection (packed; weights wave-uniform -> SGPRs) ----
    v2f aq[3], ak[3], av[3];
    #pragma unroll
    for (int jp = 0; jp < 3; ++jp) {
        aq[jp] = ((const v2f*)bqkv)[jp];
        ak[jp] = ((const v2f*)(bqkv + D))[jp];
        av[jp] = ((const v2f*)(bqkv + 2 * D))[jp];
    }
    #pragma unroll
    for (int d = 0; d < D; ++d) {
        const float* wrow = wqkv + d * 3 * D;
        v2f hd = {h1[d], h1[d]};
        #pragma unroll
        for (int jp = 0; jp < 3; ++jp) {
            aq[jp] = PKFMA(hd, ((const v2f*)wrow)[jp], aq[jp]);
            ak[jp] = PKFMA(hd, ((const v2f*)(wrow + D))[jp], ak[jp]);
            av[jp] = PKFMA(hd, ((const v2f*)(wrow + 2 * D))[jp], av[jp]);
        }
    }
    const v2f qscale = {RSQRT_D * LOG2E, RSQRT_D * LOG2E};

    // ---- stage Q, K, V^T ----
    #pragma unroll
    for (int jp = 0; jp < 3; ++jp) {
        v2f qs = aq[jp] * qscale;
        qk[0][s][jp] = pkbf(qs[1], qs[0]);
        qk[1][s][jp] = pkbf(ak[jp][1], ak[jp][0]);
    }
    qk[0][s][3] = 0; qk[0][s][4] = 0; qk[0][s][5] = 0;
    qk[1][s][3] = 0; qk[1][s][4] = 0; qk[1][s][5] = 0;
    vt[0][s] = bf16t(av[0][0]);
    vt[1][s] = bf16t(av[0][1]);
    vt[2][s] = bf16t(av[1][0]);
    vt[3][s] = bf16t(av[1][1]);
    vt[4][s] = bf16t(av[2][0]);
    vt[5][s] = bf16t(av[2][1]);
    vt[6][s] = 0x3F80;  // bf16 1.0 -> denominator column
    vt[7][s] = 0;       // zero row for clamped n-lanes
    __syncthreads();     // barrier 1: staging visible

    // ---- hoist ALL q/k fragments (qk region dies here) ----
    const int wv  = s >> 6;
    const int l15 = s & 15;
    const int lq  = (s >> 4) & 3;
    const int aoff = (lq < 2) ? lq * 8 : 16;   // quads 2/3 -> zero pad
    const int vne  = (l15 < 7) ? l15 : 7;      // 0..5=V rows, 6=ones, 7=zeros

    UA kf[8];
    #pragma unroll
    for (int jt = 0; jt < 8; ++jt)
        kf[jt].h = *(const u2*)((const char*)&qk[1][jt * 16 + l15][0] + aoff);

    const int qt0 = wv ? 1 : 0, qt1 = wv ? 6 : 7;
    const int qt2 = wv ? 2 : 3, qt3 = wv ? 5 : 4;
    UA qA1, qB1, qA2, qB2;
    qA1.h = *(const u2*)((const char*)&qk[0][qt0 * 16 + l15][0] + aoff);
    qB1.h = *(const u2*)((const char*)&qk[0][qt1 * 16 + l15][0] + aoff);
    qA2.h = *(const u2*)((const char*)&qk[0][qt2 * 16 + l15][0] + aoff);
    qB2.h = *(const u2*)((const char*)&qk[0][qt3 * 16 + l15][0] + aoff);
    __syncthreads();     // barrier 2: hoist reads done before obuf overwrites qk

    // ---- flash attention (verified core) ----
    if (wv == 0) {
        attn_pair<0, 7>(kf, vt, vne, qA1, qB1, obuf, l15, lq);
        attn_pair<3, 4>(kf, vt, vne, qA2, qB2, obuf, l15, lq);
    } else {
        attn_pair<1, 6>(kf, vt, vne, qA1, qB1, obuf, l15, lq);
        attn_pair<2, 5>(kf, vt, vne, qA2, qB2, obuf, l15, lq);
    }
    __syncthreads();     // barrier 3: obuf visible cross-wave

    // ---- epilogue: re-read x (L2-hot), per-thread packed ----
    v2f rx01 = ((const v2f*)xrow)[0];
    v2f rx23 = ((const v2f*)xrow)[1];
    v2f rx45 = ((const v2f*)xrow)[2];

    v2f o01 = *(const v2f*)&obuf[s][0];
    v2f o23 = *(const v2f*)&obuf[s][2];
    v2f o45 = *(const v2f*)&obuf[s][4];
    float invl = RCPF(obuf[s][6]);
    v2f il = {invl, invl};
    o01 *= il; o23 *= il; o45 *= il;
    float av6[D] = {o01[0], o01[1], o23[0], o23[1], o45[0], o45[1]};

    v2f xvp[3] = {rx01, rx23, rx45};
    v2f x2p[3];
    #pragma unroll
    for (int dp = 0; dp < 3; ++dp) {
        v2f o = ((const v2f*)bo)[dp];
        #pragma unroll
        for (int e = 0; e < D; ++e) {
            v2f we = ((const v2f*)(wo + e * D))[dp];
            v2f ae = {av6[e], av6[e]};
            o = PKFMA(ae, we, o);
        }
        x2p[dp] = o + xvp[dp];
    }
    float x2[D] = {x2p[0][0], x2p[0][1], x2p[1][0], x2p[1][1], x2p[2][0], x2p[2][1]};

    float m2 = 0.f;
    #pragma unroll
    for (int d = 0; d < D; ++d) m2 += x2[d];
    m2 *= (1.0f / D);
    float var2 = 0.f;
    #pragma unroll
    for (int d = 0; d < D; ++d) { float t = x2[d] - m2; var2 += t * t; }
    var2 *= (1.0f / D);
    float rstd2 = rsqrtf(var2 + EPS);
    float h2[D];
    #pragma unroll
    for (int d = 0; d < D; ++d)
        h2[d] = (x2[d] - m2) * rstd2 * ln2_w[d] + ln2_b[d];

    v2f ap[3];
    #pragma unroll
    for (int jp = 0; jp < 3; ++jp) {
        v2f a = ((const v2f*)b1)[jp];
        #pragma unroll
        for (int d = 0; d < D; ++d) {
            v2f wd = ((const v2f*)(w1 + d * D))[jp];
            v2f hd = {h2[d], h2[d]};
            a = PKFMA(hd, wd, a);
        }
        ap[jp] = a;
    }
    float g[D];
    #pragma unroll
    for (int j = 0; j < D; ++j) {
        float a = ap[j >> 1][j & 1];
        float t  = a * a;
        float in = fmaf(0.044715f * t, a, a);
        float e  = EXP2F(in * -2.3022229f);
        float r  = RCPF(1.0f + e);
        g[j] = a * r;
    }
    #pragma unroll
    for (int dp = 0; dp < 3; ++dp) {
        v2f a = ((const v2f*)b2)[dp];
        #pragma unroll
        for (int e = 0; e < D; ++e) {
            v2f we = ((const v2f*)(w2 + e * D))[dp];
            v2f ge = {g[e], g[e]};
            a = PKFMA(ge, we, a);
        }
        ((v2f*)orow)[dp] = x2p[dp] + a;
    }
}

extern "C" void kernel_launch(void* const* d_in, const int* in_sizes, int n_in,
                              void* d_out, int out_size, void* d_ws, size_t ws_size,
                              hipStream_t stream) {
    const float* x     = (const float*)d_in[0];
    const float* ln1_w = (const float*)d_in[1];
    const float* ln1_b = (const float*)d_in[2];
    const float* wqkv  = (const float*)d_in[3];
    const float* bqkv  = (const float*)d_in[4];
    const float* wo    = (const float*)d_in[5];
    const float* bo    = (const float*)d_in[6];
    const float* ln2_w = (const float*)d_in[7];
    const float* ln2_b = (const float*)d_in[8];
    const float* w1    = (const float*)d_in[9];
    const float* b1    = (const float*)d_in[10];
    const float* w2    = (const float*)d_in[11];
    const float* b2    = (const float*)d_in[12];
    float* out = (float*)d_out;

    const int B = in_sizes[0] / (S * D);
    txblock_kernel<<<B, S, 0, stream>>>(x, ln1_w, ln1_b, wqkv, bqkv, wo, bo,
                                        ln2_w, ln2_b, w1, b1, w2, b2, out);
}